// Round 1
// baseline (14256.871 us; speedup 1.0000x reference)
//
#include <hip/hip_runtime.h>
#include <hip/hip_bf16.h>
#include <math.h>

#define B_ 4
#define T_ 2048
#define E_ 512
#define H_ 8
#define D_ 64
#define L_ 4
#define V_ 1024
#define NROWS (B_*T_)   // 8192

// ---------------- embedding: x = wte[idx] + wpe[t] ----------------
__global__ void embed_kernel(const int* __restrict__ idx, const float* __restrict__ wte,
                             const float* __restrict__ wpe, float* __restrict__ x) {
    int i = blockIdx.x * blockDim.x + threadIdx.x;   // over NROWS*E_
    int row = i / E_;
    int e = i - row * E_;
    int t = row & (T_ - 1);
    int id = idx[row];
    x[i] = wte[id * E_ + e] + wpe[t * E_ + e];
}

// ---------------- layernorm: one block (256 thr) per row of E_=512 ----------------
__global__ __launch_bounds__(256) void layernorm_kernel(const float* __restrict__ x,
                                 const float* __restrict__ w, const float* __restrict__ b,
                                 float* __restrict__ out) {
    __shared__ float red[256];
    int row = blockIdx.x;
    int tid = threadIdx.x;
    const float* xr = x + (size_t)row * E_;
    float v0 = xr[tid], v1 = xr[tid + 256];
    red[tid] = v0 + v1;
    __syncthreads();
    for (int st = 128; st > 0; st >>= 1) { if (tid < st) red[tid] += red[tid + st]; __syncthreads(); }
    float mean = red[0] * (1.0f / E_);
    __syncthreads();
    float d0 = v0 - mean, d1 = v1 - mean;
    red[tid] = d0 * d0 + d1 * d1;
    __syncthreads();
    for (int st = 128; st > 0; st >>= 1) { if (tid < st) red[tid] += red[tid + st]; __syncthreads(); }
    float rstd = rsqrtf(red[0] * (1.0f / E_) + 1e-5f);
    float* outr = out + (size_t)row * E_;
    outr[tid]       = d0 * rstd * w[tid]       + b[tid];
    outr[tid + 256] = d1 * rstd * w[tid + 256] + b[tid + 256];
}

// ---------------- GEMM (NT): C[m,n] = f(A[m,:]·W[n,:] + bias[n]) (+resid) ----------------
#define BM 64
#define BN 64
#define BK 16

template<int ACT, bool RESID, bool BIAS>
__global__ __launch_bounds__(256) void gemm_nt(const float* __restrict__ A, const float* __restrict__ W,
                        const float* __restrict__ bias, float* __restrict__ C,
                        int M, int N, int K) {
    __shared__ __align__(16) float As[BK][BM];
    __shared__ __align__(16) float Ws[BK][BN];
    int tid = threadIdx.x;
    int tx = tid & 15, ty = tid >> 4;
    int m0 = blockIdx.y * BM;
    int n0 = blockIdx.x * BN;
    float acc[4][4] = {};

    int lr  = tid >> 2;          // 0..63 row within tile
    int lc4 = (tid & 3) * 4;     // 0,4,8,12 col within K-tile

    for (int k0 = 0; k0 < K; k0 += BK) {
        float4 av = *(const float4*)(A + (size_t)(m0 + lr) * K + k0 + lc4);
        float4 wv = *(const float4*)(W + (size_t)(n0 + lr) * K + k0 + lc4);
        As[lc4 + 0][lr] = av.x; As[lc4 + 1][lr] = av.y; As[lc4 + 2][lr] = av.z; As[lc4 + 3][lr] = av.w;
        Ws[lc4 + 0][lr] = wv.x; Ws[lc4 + 1][lr] = wv.y; Ws[lc4 + 2][lr] = wv.z; Ws[lc4 + 3][lr] = wv.w;
        __syncthreads();
        #pragma unroll
        for (int kk = 0; kk < BK; ++kk) {
            float4 a = *(const float4*)&As[kk][ty * 4];
            float4 w4 = *(const float4*)&Ws[kk][tx * 4];
            float ar[4] = {a.x, a.y, a.z, a.w};
            float wr[4] = {w4.x, w4.y, w4.z, w4.w};
            #pragma unroll
            for (int i = 0; i < 4; ++i)
                #pragma unroll
                for (int j = 0; j < 4; ++j)
                    acc[i][j] += ar[i] * wr[j];
        }
        __syncthreads();
    }
    #pragma unroll
    for (int i = 0; i < 4; ++i) {
        int m = m0 + ty * 4 + i;
        #pragma unroll
        for (int j = 0; j < 4; ++j) {
            int n = n0 + tx * 4 + j;
            float v = acc[i][j];
            if (BIAS) v += bias[n];
            if (ACT == 1) v = 0.5f * v * (1.0f + erff(v * 0.70710678118654752f));
            if (RESID) v += C[(size_t)m * N + n];
            C[(size_t)m * N + n] = v;
        }
    }
}

// ---------------- causal attention, one block (256 thr) per (b,h,q) ----------------
__global__ __launch_bounds__(256) void attn_kernel(const float* __restrict__ qkv, float* __restrict__ y) {
    __shared__ float q_s[D_];
    __shared__ float p_s[256];
    __shared__ float red[256];
    int tq = blockIdx.x, h = blockIdx.y, b = blockIdx.z;
    int tid = threadIdx.x;
    const size_t rowq = (size_t)(b * T_ + tq) * (3 * E_);
    if (tid < D_) q_s[tid] = qkv[rowq + h * D_ + tid];
    __syncthreads();
    int d = tid & 63, g = tid >> 6;
    float accp = 0.0f;
    float m = -INFINITY, l = 0.0f;
    const float scale = 0.125f;   // 1/sqrt(64)

    for (int kk0 = 0; kk0 <= tq; kk0 += 256) {
        int nk = min(256, tq + 1 - kk0);
        float s = -INFINITY;
        if (tid < nk) {
            const float* kr = qkv + (size_t)(b * T_ + kk0 + tid) * (3 * E_) + E_ + h * D_;
            float acc = 0.0f;
            #pragma unroll
            for (int dd = 0; dd < D_; dd += 4) {
                float4 kv = *(const float4*)(kr + dd);
                acc += q_s[dd] * kv.x + q_s[dd + 1] * kv.y + q_s[dd + 2] * kv.z + q_s[dd + 3] * kv.w;
            }
            s = acc * scale;
        }
        // block max
        red[tid] = s;
        __syncthreads();
        for (int st = 128; st > 0; st >>= 1) { if (tid < st) red[tid] = fmaxf(red[tid], red[tid + st]); __syncthreads(); }
        float m_new = fmaxf(m, red[0]);
        __syncthreads();
        float p = (tid < nk) ? expf(s - m_new) : 0.0f;
        p_s[tid] = p;
        red[tid] = p;
        __syncthreads();
        for (int st = 128; st > 0; st >>= 1) { if (tid < st) red[tid] += red[tid + st]; __syncthreads(); }
        float corr = expf(m - m_new);
        l = l * corr + red[0];
        m = m_new;
        accp *= corr;
        for (int j = g; j < nk; j += 4) {
            const float* vr = qkv + (size_t)(b * T_ + kk0 + j) * (3 * E_) + 2 * E_ + h * D_;
            accp += p_s[j] * vr[d];
        }
        __syncthreads();
    }
    // combine the 4 groups
    p_s[tid] = accp;
    __syncthreads();
    if (tid < D_) {
        float v = p_s[tid] + p_s[64 + tid] + p_s[128 + tid] + p_s[192 + tid];
        y[(size_t)(b * T_ + tq) * E_ + h * D_ + tid] = v / l;
    }
}

extern "C" void kernel_launch(void* const* d_in, const int* in_sizes, int n_in,
                              void* d_out, int out_size, void* d_ws, size_t ws_size,
                              hipStream_t stream) {
    const int*   idx    = (const int*)d_in[0];
    const float* wte    = (const float*)d_in[1];
    const float* wpe    = (const float*)d_in[2];
    const float* ln1_w  = (const float*)d_in[3];
    const float* ln1_b  = (const float*)d_in[4];
    const float* attn_w = (const float*)d_in[5];
    const float* attn_b = (const float*)d_in[6];
    const float* proj_w = (const float*)d_in[7];
    const float* proj_b = (const float*)d_in[8];
    const float* ln2_w  = (const float*)d_in[9];
    const float* ln2_b  = (const float*)d_in[10];
    const float* fc_w   = (const float*)d_in[11];
    const float* fc_b   = (const float*)d_in[12];
    const float* fc2_w  = (const float*)d_in[13];
    const float* fc2_b  = (const float*)d_in[14];
    const float* lnf_w  = (const float*)d_in[15];
    const float* lnf_b  = (const float*)d_in[16];
    float* out = (float*)d_out;

    // workspace layout (floats): x[NROWS*E] | h[NROWS*E] | big[NROWS*4E]  = 100.7 MB
    float* x   = (float*)d_ws;
    float* h   = x + (size_t)NROWS * E_;
    float* big = h + (size_t)NROWS * E_;

    embed_kernel<<<NROWS * E_ / 256, 256, 0, stream>>>(idx, wte, wpe, x);

    for (int l = 0; l < L_; ++l) {
        layernorm_kernel<<<NROWS, 256, 0, stream>>>(x, ln1_w + l * E_, ln1_b + l * E_, h);
        gemm_nt<0, false, true><<<dim3(3 * E_ / BN, NROWS / BM), 256, 0, stream>>>(
            h, attn_w + (size_t)l * 3 * E_ * E_, attn_b + l * 3 * E_, big, NROWS, 3 * E_, E_);
        attn_kernel<<<dim3(T_, H_, B_), 256, 0, stream>>>(big, h);
        gemm_nt<0, true, true><<<dim3(E_ / BN, NROWS / BM), 256, 0, stream>>>(
            h, proj_w + (size_t)l * E_ * E_, proj_b + l * E_, x, NROWS, E_, E_);
        layernorm_kernel<<<NROWS, 256, 0, stream>>>(x, ln2_w + l * E_, ln2_b + l * E_, h);
        gemm_nt<1, false, true><<<dim3(4 * E_ / BN, NROWS / BM), 256, 0, stream>>>(
            h, fc_w + (size_t)l * 4 * E_ * E_, fc_b + l * 4 * E_, big, NROWS, 4 * E_, E_);
        gemm_nt<0, true, true><<<dim3(E_ / BN, NROWS / BM), 256, 0, stream>>>(
            big, fc2_w + (size_t)l * E_ * 4 * E_, fc2_b + l * E_, x, NROWS, E_, 4 * E_);
    }
    layernorm_kernel<<<NROWS, 256, 0, stream>>>(x, lnf_w, lnf_b, h);
    gemm_nt<0, false, false><<<dim3(V_ / BN, NROWS / BM), 256, 0, stream>>>(
        h, wte, nullptr, out, NROWS, V_, E_);
}

// Round 2
// 5230.666 us; speedup vs baseline: 2.7256x; 2.7256x over previous
//
#include <hip/hip_runtime.h>
#include <hip/hip_bf16.h>
#include <math.h>

#define B_ 4
#define T_ 2048
#define E_ 512
#define H_ 8
#define D_ 64
#define L_ 4
#define V_ 1024
#define NROWS (B_*T_)   // 8192

// ---------------- embedding: x = wte[idx] + wpe[t] ----------------
__global__ void embed_kernel(const int* __restrict__ idx, const float* __restrict__ wte,
                             const float* __restrict__ wpe, float* __restrict__ x) {
    int i = blockIdx.x * blockDim.x + threadIdx.x;   // over NROWS*E_
    int row = i / E_;
    int e = i - row * E_;
    int t = row & (T_ - 1);
    int id = idx[row];
    x[i] = wte[id * E_ + e] + wpe[t * E_ + e];
}

// ---------------- layernorm: one block (256 thr) per row of E_=512 ----------------
__global__ __launch_bounds__(256) void layernorm_kernel(const float* __restrict__ x,
                                 const float* __restrict__ w, const float* __restrict__ b,
                                 float* __restrict__ out) {
    __shared__ float red[256];
    int row = blockIdx.x;
    int tid = threadIdx.x;
    const float* xr = x + (size_t)row * E_;
    float v0 = xr[tid], v1 = xr[tid + 256];
    red[tid] = v0 + v1;
    __syncthreads();
    for (int st = 128; st > 0; st >>= 1) { if (tid < st) red[tid] += red[tid + st]; __syncthreads(); }
    float mean = red[0] * (1.0f / E_);
    __syncthreads();
    float d0 = v0 - mean, d1 = v1 - mean;
    red[tid] = d0 * d0 + d1 * d1;
    __syncthreads();
    for (int st = 128; st > 0; st >>= 1) { if (tid < st) red[tid] += red[tid + st]; __syncthreads(); }
    float rstd = rsqrtf(red[0] * (1.0f / E_) + 1e-5f);
    float* outr = out + (size_t)row * E_;
    outr[tid]       = d0 * rstd * w[tid]       + b[tid];
    outr[tid + 256] = d1 * rstd * w[tid + 256] + b[tid + 256];
}

// ---------------- GEMM (NT): C[m,n] = f(A[m,:]·W[n,:] + bias[n]) (+resid) ----------------
#define BM 64
#define BN 64
#define BK 16

template<int ACT, bool RESID, bool BIAS>
__global__ __launch_bounds__(256) void gemm_nt(const float* __restrict__ A, const float* __restrict__ W,
                        const float* __restrict__ bias, float* __restrict__ C,
                        int M, int N, int K) {
    __shared__ __align__(16) float As[BK][BM];
    __shared__ __align__(16) float Ws[BK][BN];
    int tid = threadIdx.x;
    int tx = tid & 15, ty = tid >> 4;
    int m0 = blockIdx.y * BM;
    int n0 = blockIdx.x * BN;
    float acc[4][4] = {};

    int lr  = tid >> 2;          // 0..63 row within tile
    int lc4 = (tid & 3) * 4;     // 0,4,8,12 col within K-tile

    for (int k0 = 0; k0 < K; k0 += BK) {
        float4 av = *(const float4*)(A + (size_t)(m0 + lr) * K + k0 + lc4);
        float4 wv = *(const float4*)(W + (size_t)(n0 + lr) * K + k0 + lc4);
        As[lc4 + 0][lr] = av.x; As[lc4 + 1][lr] = av.y; As[lc4 + 2][lr] = av.z; As[lc4 + 3][lr] = av.w;
        Ws[lc4 + 0][lr] = wv.x; Ws[lc4 + 1][lr] = wv.y; Ws[lc4 + 2][lr] = wv.z; Ws[lc4 + 3][lr] = wv.w;
        __syncthreads();
        #pragma unroll
        for (int kk = 0; kk < BK; ++kk) {
            float4 a = *(const float4*)&As[kk][ty * 4];
            float4 w4 = *(const float4*)&Ws[kk][tx * 4];
            float ar[4] = {a.x, a.y, a.z, a.w};
            float wr[4] = {w4.x, w4.y, w4.z, w4.w};
            #pragma unroll
            for (int i = 0; i < 4; ++i)
                #pragma unroll
                for (int j = 0; j < 4; ++j)
                    acc[i][j] += ar[i] * wr[j];
        }
        __syncthreads();
    }
    #pragma unroll
    for (int i = 0; i < 4; ++i) {
        int m = m0 + ty * 4 + i;
        #pragma unroll
        for (int j = 0; j < 4; ++j) {
            int n = n0 + tx * 4 + j;
            float v = acc[i][j];
            if (BIAS) v += bias[n];
            if (ACT == 1) v = 0.5f * v * (1.0f + erff(v * 0.70710678118654752f));
            if (RESID) v += C[(size_t)m * N + n];
            C[(size_t)m * N + n] = v;
        }
    }
}

// ---------------- flash attention: one block per (b, h, q-tile of 64) ----------------
// 256 threads = 16x16; thread (ty,tx) owns rows ty*4..+3, cols/dims tx*4..+3.
__global__ __launch_bounds__(256) void attn_flash(const float* __restrict__ qkv, float* __restrict__ y) {
    __shared__ __align__(16) float QsT[D_][68];   // [dd][row]
    __shared__ __align__(16) float KsT[D_][68];   // [dd][col]
    __shared__ __align__(16) float Vs[64][68];    // [k][dd]
    __shared__ __align__(16) float PsT[64][68];   // [k][row]
    int qi = 31 - blockIdx.x;                     // heaviest first
    int h = blockIdx.y, b = blockIdx.z;
    int q0 = qi * 64;
    int tid = threadIdx.x;
    int tx = tid & 15, ty = tid >> 4;

    // stage Q transposed
    #pragma unroll
    for (int it = 0; it < 4; ++it) {
        int flat = it * 256 + tid;
        int r = flat >> 4, d4 = (flat & 15) * 4;
        float4 q = *(const float4*)(qkv + (size_t)(b * T_ + q0 + r) * (3 * E_) + h * D_ + d4);
        QsT[d4 + 0][r] = q.x; QsT[d4 + 1][r] = q.y; QsT[d4 + 2][r] = q.z; QsT[d4 + 3][r] = q.w;
    }

    float O[4][4] = {};
    float m_[4], l_[4];
    #pragma unroll
    for (int i = 0; i < 4; ++i) { m_[i] = -INFINITY; l_[i] = 0.0f; }

    for (int kt = 0; kt <= qi; ++kt) {
        int k0 = kt * 64;
        __syncthreads();   // prev-iter PV done (Vs/PsT free); also orders QsT stage on iter 0
        #pragma unroll
        for (int it = 0; it < 4; ++it) {
            int flat = it * 256 + tid;
            int r = flat >> 4, d4 = (flat & 15) * 4;
            size_t base = (size_t)(b * T_ + k0 + r) * (3 * E_) + h * D_ + d4;
            float4 kv = *(const float4*)(qkv + base + E_);
            KsT[d4 + 0][r] = kv.x; KsT[d4 + 1][r] = kv.y; KsT[d4 + 2][r] = kv.z; KsT[d4 + 3][r] = kv.w;
            float4 vv = *(const float4*)(qkv + base + 2 * E_);
            *(float4*)&Vs[r][d4] = vv;
        }
        __syncthreads();

        // S = Q K^T  (4x4 per thread)
        float s[4][4] = {};
        #pragma unroll 8
        for (int dd = 0; dd < D_; ++dd) {
            float4 qv = *(const float4*)&QsT[dd][ty * 4];
            float4 kv = *(const float4*)&KsT[dd][tx * 4];
            float qa[4] = {qv.x, qv.y, qv.z, qv.w};
            float ka[4] = {kv.x, kv.y, kv.z, kv.w};
            #pragma unroll
            for (int i = 0; i < 4; ++i)
                #pragma unroll
                for (int j = 0; j < 4; ++j)
                    s[i][j] += qa[i] * ka[j];
        }

        const bool diag = (kt == qi);
        #pragma unroll
        for (int i = 0; i < 4; ++i) {
            int row = ty * 4 + i;
            float rm = -INFINITY;
            #pragma unroll
            for (int j = 0; j < 4; ++j) {
                float sv = s[i][j] * 0.125f;
                if (diag && (tx * 4 + j > row)) sv = -INFINITY;
                s[i][j] = sv;
                rm = fmaxf(rm, sv);
            }
            rm = fmaxf(rm, __shfl_xor(rm, 1));
            rm = fmaxf(rm, __shfl_xor(rm, 2));
            rm = fmaxf(rm, __shfl_xor(rm, 4));
            rm = fmaxf(rm, __shfl_xor(rm, 8));
            float mnew = fmaxf(m_[i], rm);
            float corr = __expf(m_[i] - mnew);
            float rl = 0.0f;
            #pragma unroll
            for (int j = 0; j < 4; ++j) { s[i][j] = __expf(s[i][j] - mnew); rl += s[i][j]; }
            rl += __shfl_xor(rl, 1);
            rl += __shfl_xor(rl, 2);
            rl += __shfl_xor(rl, 4);
            rl += __shfl_xor(rl, 8);
            l_[i] = l_[i] * corr + rl;
            m_[i] = mnew;
            #pragma unroll
            for (int j = 0; j < 4; ++j) O[i][j] *= corr;
        }

        // write P transposed: PsT[col][row]
        #pragma unroll
        for (int j = 0; j < 4; ++j) {
            float4 col = make_float4(s[0][j], s[1][j], s[2][j], s[3][j]);
            *(float4*)&PsT[tx * 4 + j][ty * 4] = col;
        }
        __syncthreads();

        // O += P V  (4x4 per thread)
        #pragma unroll 8
        for (int k = 0; k < 64; ++k) {
            float4 pv = *(const float4*)&PsT[k][ty * 4];
            float4 vv = *(const float4*)&Vs[k][tx * 4];
            float pa[4] = {pv.x, pv.y, pv.z, pv.w};
            float va[4] = {vv.x, vv.y, vv.z, vv.w};
            #pragma unroll
            for (int i = 0; i < 4; ++i)
                #pragma unroll
                for (int j = 0; j < 4; ++j)
                    O[i][j] += pa[i] * va[j];
        }
    }

    #pragma unroll
    for (int i = 0; i < 4; ++i) {
        float inv = 1.0f / l_[i];
        float4 o = make_float4(O[i][0] * inv, O[i][1] * inv, O[i][2] * inv, O[i][3] * inv);
        *(float4*)(y + (size_t)(b * T_ + q0 + ty * 4 + i) * E_ + h * D_ + tx * 4) = o;
    }
}

extern "C" void kernel_launch(void* const* d_in, const int* in_sizes, int n_in,
                              void* d_out, int out_size, void* d_ws, size_t ws_size,
                              hipStream_t stream) {
    const int*   idx    = (const int*)d_in[0];
    const float* wte    = (const float*)d_in[1];
    const float* wpe    = (const float*)d_in[2];
    const float* ln1_w  = (const float*)d_in[3];
    const float* ln1_b  = (const float*)d_in[4];
    const float* attn_w = (const float*)d_in[5];
    const float* attn_b = (const float*)d_in[6];
    const float* proj_w = (const float*)d_in[7];
    const float* proj_b = (const float*)d_in[8];
    const float* ln2_w  = (const float*)d_in[9];
    const float* ln2_b  = (const float*)d_in[10];
    const float* fc_w   = (const float*)d_in[11];
    const float* fc_b   = (const float*)d_in[12];
    const float* fc2_w  = (const float*)d_in[13];
    const float* fc2_b  = (const float*)d_in[14];
    const float* lnf_w  = (const float*)d_in[15];
    const float* lnf_b  = (const float*)d_in[16];
    float* out = (float*)d_out;

    // workspace layout (floats): x[NROWS*E] | h[NROWS*E] | big[NROWS*4E]  = 100.7 MB
    float* x   = (float*)d_ws;
    float* h   = x + (size_t)NROWS * E_;
    float* big = h + (size_t)NROWS * E_;

    embed_kernel<<<NROWS * E_ / 256, 256, 0, stream>>>(idx, wte, wpe, x);

    for (int l = 0; l < L_; ++l) {
        layernorm_kernel<<<NROWS, 256, 0, stream>>>(x, ln1_w + l * E_, ln1_b + l * E_, h);
        gemm_nt<0, false, true><<<dim3(3 * E_ / BN, NROWS / BM), 256, 0, stream>>>(
            h, attn_w + (size_t)l * 3 * E_ * E_, attn_b + l * 3 * E_, big, NROWS, 3 * E_, E_);
        attn_flash<<<dim3(T_ / 64, H_, B_), 256, 0, stream>>>(big, h);
        gemm_nt<0, true, true><<<dim3(E_ / BN, NROWS / BM), 256, 0, stream>>>(
            h, proj_w + (size_t)l * E_ * E_, proj_b + l * E_, x, NROWS, E_, E_);
        layernorm_kernel<<<NROWS, 256, 0, stream>>>(x, ln2_w + l * E_, ln2_b + l * E_, h);
        gemm_nt<1, false, true><<<dim3(4 * E_ / BN, NROWS / BM), 256, 0, stream>>>(
            h, fc_w + (size_t)l * 4 * E_ * E_, fc_b + l * 4 * E_, big, NROWS, 4 * E_, E_);
        gemm_nt<0, true, true><<<dim3(E_ / BN, NROWS / BM), 256, 0, stream>>>(
            big, fc2_w + (size_t)l * E_ * 4 * E_, fc2_b + l * E_, x, NROWS, E_, 4 * E_);
    }
    layernorm_kernel<<<NROWS, 256, 0, stream>>>(x, lnf_w, lnf_b, h);
    gemm_nt<0, false, false><<<dim3(V_ / BN, NROWS / BM), 256, 0, stream>>>(
        h, wte, nullptr, out, NROWS, V_, E_);
}

// Round 3
// 2824.163 us; speedup vs baseline: 5.0482x; 1.8521x over previous
//
#include <hip/hip_runtime.h>
#include <hip/hip_bf16.h>
#include <math.h>

#define B_ 4
#define T_ 2048
#define E_ 512
#define H_ 8
#define D_ 64
#define L_ 4
#define V_ 1024
#define NROWS (B_*T_)   // 8192

typedef __hip_bfloat16 bf16;
typedef __attribute__((ext_vector_type(8))) short bf16x8;
typedef __attribute__((ext_vector_type(4))) float f32x4;

__device__ __forceinline__ float bf2f(short u) {
    union { float f; unsigned int i; } t;
    t.i = ((unsigned int)(unsigned short)u) << 16;
    return t.f;
}

__device__ __forceinline__ void gload_lds16(const bf16* g, bf16* l) {
    __builtin_amdgcn_global_load_lds((const __attribute__((address_space(1))) void*)g,
                                     (__attribute__((address_space(3))) void*)l, 16, 0, 0);
}

// ---------------- fp32 -> bf16 convert (n multiple of 1024) ----------------
__global__ void f2bf_kernel(const float* __restrict__ in, bf16* __restrict__ out) {
    int i = (blockIdx.x * blockDim.x + threadIdx.x) * 4;
    float4 v = *(const float4*)(in + i);
    union { bf16 h[4]; uint2 u; } t;
    t.h[0] = __float2bfloat16(v.x); t.h[1] = __float2bfloat16(v.y);
    t.h[2] = __float2bfloat16(v.z); t.h[3] = __float2bfloat16(v.w);
    *(uint2*)(out + i) = t.u;
}

// ---------------- embedding: x = wte[idx] + wpe[t] ----------------
__global__ void embed_kernel(const int* __restrict__ idx, const float* __restrict__ wte,
                             const float* __restrict__ wpe, float* __restrict__ x) {
    int i = blockIdx.x * blockDim.x + threadIdx.x;
    int row = i / E_;
    int e = i - row * E_;
    int t = row & (T_ - 1);
    int id = idx[row];
    x[i] = wte[id * E_ + e] + wpe[t * E_ + e];
}

// ---------------- layernorm: fp32 in, bf16 out ----------------
__global__ __launch_bounds__(256) void layernorm_kernel(const float* __restrict__ x,
                                 const float* __restrict__ w, const float* __restrict__ b,
                                 bf16* __restrict__ out) {
    __shared__ float red[256];
    int row = blockIdx.x;
    int tid = threadIdx.x;
    const float* xr = x + (size_t)row * E_;
    float v0 = xr[tid], v1 = xr[tid + 256];
    red[tid] = v0 + v1;
    __syncthreads();
    for (int st = 128; st > 0; st >>= 1) { if (tid < st) red[tid] += red[tid + st]; __syncthreads(); }
    float mean = red[0] * (1.0f / E_);
    __syncthreads();
    float d0 = v0 - mean, d1 = v1 - mean;
    red[tid] = d0 * d0 + d1 * d1;
    __syncthreads();
    for (int st = 128; st > 0; st >>= 1) { if (tid < st) red[tid] += red[tid + st]; __syncthreads(); }
    float rstd = rsqrtf(red[0] * (1.0f / E_) + 1e-5f);
    bf16* outr = out + (size_t)row * E_;
    outr[tid]       = __float2bfloat16(d0 * rstd * w[tid]       + b[tid]);
    outr[tid + 256] = __float2bfloat16(d1 * rstd * w[tid + 256] + b[tid + 256]);
}

// ---------------- bf16 MFMA GEMM (NT): C[m,n] = f(A[m,:]·W[n,:] + bias) ----------------
// m97 structure: 128x128 tile, BK=32, 4 waves (2x2 of 64x64), global_load_lds w16.
// OMODE: 0 = fp32 store, 1 = bf16 store, 2 = fp32 residual accumulate
template<int ACT, int OMODE, bool BIAS>
__global__ __launch_bounds__(256) void gemm_mfma(const bf16* __restrict__ A, const bf16* __restrict__ W,
        const float* __restrict__ bias, float* __restrict__ Cf, bf16* __restrict__ Cb,
        int M, int N, int K) {
    __shared__ __align__(16) bf16 As[128][32];
    __shared__ __align__(16) bf16 Bs[128][32];
    int tid = threadIdx.x;
    int lane = tid & 63, wid = tid >> 6;
    int wm = (wid >> 1) * 64, wn = (wid & 1) * 64;
    int m0 = blockIdx.y * 128, n0 = blockIdx.x * 128;

    // staging: wave wid covers tile rows [wid*32, wid*32+32) of both A and B
    int srow = wid * 32 + (lane >> 2);
    int scol = (lane & 3) * 8;
    const bf16* ga = A + (size_t)(m0 + srow) * K + scol;
    const bf16* gb = W + (size_t)(n0 + srow) * K + scol;
    int fr = lane & 15, fk = (lane >> 4) * 8;

    f32x4 acc[4][4];
    #pragma unroll
    for (int i = 0; i < 4; ++i)
        #pragma unroll
        for (int j = 0; j < 4; ++j) acc[i][j] = (f32x4){0.f, 0.f, 0.f, 0.f};

    for (int k0 = 0; k0 < K; k0 += 32) {
        gload_lds16(ga,          &As[wid * 32][0]);
        gload_lds16(ga + 16 * K, &As[wid * 32 + 16][0]);
        gload_lds16(gb,          &Bs[wid * 32][0]);
        gload_lds16(gb + 16 * K, &Bs[wid * 32 + 16][0]);
        ga += 32; gb += 32;
        __syncthreads();   // drains vmcnt -> tiles ready
        bf16x8 af[4], bff[4];
        #pragma unroll
        for (int i = 0; i < 4; ++i) af[i]  = *(const bf16x8*)&As[wm + i * 16 + fr][fk];
        #pragma unroll
        for (int j = 0; j < 4; ++j) bff[j] = *(const bf16x8*)&Bs[wn + j * 16 + fr][fk];
        #pragma unroll
        for (int i = 0; i < 4; ++i)
            #pragma unroll
            for (int j = 0; j < 4; ++j)
                acc[i][j] = __builtin_amdgcn_mfma_f32_16x16x32_bf16(af[i], bff[j], acc[i][j], 0, 0, 0);
        __syncthreads();   // frag reads done -> safe to restage
    }

    int orow = m0 + wm + (lane >> 4) * 4;
    int ocol = n0 + wn + (lane & 15);
    #pragma unroll
    for (int i = 0; i < 4; ++i) {
        #pragma unroll
        for (int j = 0; j < 4; ++j) {
            #pragma unroll
            for (int r = 0; r < 4; ++r) {
                int row = orow + i * 16 + r;
                int col = ocol + j * 16;
                float v = acc[i][j][r];
                if (BIAS) v += bias[col];
                if (ACT == 1) v = 0.5f * v * (1.0f + erff(v * 0.70710678118654752f));
                size_t off = (size_t)row * N + col;
                if (OMODE == 0) Cf[off] = v;
                else if (OMODE == 1) Cb[off] = __float2bfloat16(v);
                else Cf[off] += v;
            }
        }
    }
}

// ---------------- flash attention: bf16 qkv in, bf16 y out ----------------
__global__ __launch_bounds__(256) void attn_flash(const bf16* __restrict__ qkv, bf16* __restrict__ y) {
    __shared__ __align__(16) float QsT[D_][68];   // [dd][row]
    __shared__ __align__(16) float KsT[D_][68];   // [dd][col]
    __shared__ __align__(16) float Vs[64][68];    // [k][dd]
    __shared__ __align__(16) float PsT[64][68];   // [k][row]
    int qi = 31 - blockIdx.x;                     // heaviest first
    int h = blockIdx.y, b = blockIdx.z;
    int q0 = qi * 64;
    int tid = threadIdx.x;
    int tx = tid & 15, ty = tid >> 4;

    // stage Q transposed
    #pragma unroll
    for (int it = 0; it < 4; ++it) {
        int flat = it * 256 + tid;
        int r = flat >> 4, d4 = (flat & 15) * 4;
        short4 q = *(const short4*)(qkv + (size_t)(b * T_ + q0 + r) * (3 * E_) + h * D_ + d4);
        QsT[d4 + 0][r] = bf2f(q.x); QsT[d4 + 1][r] = bf2f(q.y);
        QsT[d4 + 2][r] = bf2f(q.z); QsT[d4 + 3][r] = bf2f(q.w);
    }

    float O[4][4] = {};
    float m_[4], l_[4];
    #pragma unroll
    for (int i = 0; i < 4; ++i) { m_[i] = -INFINITY; l_[i] = 0.0f; }

    for (int kt = 0; kt <= qi; ++kt) {
        int k0 = kt * 64;
        __syncthreads();
        #pragma unroll
        for (int it = 0; it < 4; ++it) {
            int flat = it * 256 + tid;
            int r = flat >> 4, d4 = (flat & 15) * 4;
            size_t base = (size_t)(b * T_ + k0 + r) * (3 * E_) + h * D_ + d4;
            short4 kv = *(const short4*)(qkv + base + E_);
            KsT[d4 + 0][r] = bf2f(kv.x); KsT[d4 + 1][r] = bf2f(kv.y);
            KsT[d4 + 2][r] = bf2f(kv.z); KsT[d4 + 3][r] = bf2f(kv.w);
            short4 vv = *(const short4*)(qkv + base + 2 * E_);
            Vs[r][d4 + 0] = bf2f(vv.x); Vs[r][d4 + 1] = bf2f(vv.y);
            Vs[r][d4 + 2] = bf2f(vv.z); Vs[r][d4 + 3] = bf2f(vv.w);
        }
        __syncthreads();

        float s[4][4] = {};
        #pragma unroll 8
        for (int dd = 0; dd < D_; ++dd) {
            float4 qv = *(const float4*)&QsT[dd][ty * 4];
            float4 kv = *(const float4*)&KsT[dd][tx * 4];
            float qa[4] = {qv.x, qv.y, qv.z, qv.w};
            float ka[4] = {kv.x, kv.y, kv.z, kv.w};
            #pragma unroll
            for (int i = 0; i < 4; ++i)
                #pragma unroll
                for (int j = 0; j < 4; ++j)
                    s[i][j] += qa[i] * ka[j];
        }

        const bool diag = (kt == qi);
        #pragma unroll
        for (int i = 0; i < 4; ++i) {
            int row = ty * 4 + i;
            float rm = -INFINITY;
            #pragma unroll
            for (int j = 0; j < 4; ++j) {
                float sv = s[i][j] * 0.125f;
                if (diag && (tx * 4 + j > row)) sv = -INFINITY;
                s[i][j] = sv;
                rm = fmaxf(rm, sv);
            }
            rm = fmaxf(rm, __shfl_xor(rm, 1));
            rm = fmaxf(rm, __shfl_xor(rm, 2));
            rm = fmaxf(rm, __shfl_xor(rm, 4));
            rm = fmaxf(rm, __shfl_xor(rm, 8));
            float mnew = fmaxf(m_[i], rm);
            float corr = __expf(m_[i] - mnew);
            float rl = 0.0f;
            #pragma unroll
            for (int j = 0; j < 4; ++j) { s[i][j] = __expf(s[i][j] - mnew); rl += s[i][j]; }
            rl += __shfl_xor(rl, 1);
            rl += __shfl_xor(rl, 2);
            rl += __shfl_xor(rl, 4);
            rl += __shfl_xor(rl, 8);
            l_[i] = l_[i] * corr + rl;
            m_[i] = mnew;
            #pragma unroll
            for (int j = 0; j < 4; ++j) O[i][j] *= corr;
        }

        #pragma unroll
        for (int j = 0; j < 4; ++j) {
            float4 col = make_float4(s[0][j], s[1][j], s[2][j], s[3][j]);
            *(float4*)&PsT[tx * 4 + j][ty * 4] = col;
        }
        __syncthreads();

        #pragma unroll 8
        for (int k = 0; k < 64; ++k) {
            float4 pv = *(const float4*)&PsT[k][ty * 4];
            float4 vv = *(const float4*)&Vs[k][tx * 4];
            float pa[4] = {pv.x, pv.y, pv.z, pv.w};
            float va[4] = {vv.x, vv.y, vv.z, vv.w};
            #pragma unroll
            for (int i = 0; i < 4; ++i)
                #pragma unroll
                for (int j = 0; j < 4; ++j)
                    O[i][j] += pa[i] * va[j];
        }
    }

    #pragma unroll
    for (int i = 0; i < 4; ++i) {
        float inv = 1.0f / l_[i];
        union { bf16 hb[4]; uint2 u; } o;
        #pragma unroll
        for (int j = 0; j < 4; ++j) o.hb[j] = __float2bfloat16(O[i][j] * inv);
        *(uint2*)(y + (size_t)(b * T_ + q0 + ty * 4 + i) * E_ + h * D_ + tx * 4) = o.u;
    }
}

extern "C" void kernel_launch(void* const* d_in, const int* in_sizes, int n_in,
                              void* d_out, int out_size, void* d_ws, size_t ws_size,
                              hipStream_t stream) {
    const int*   idx    = (const int*)d_in[0];
    const float* wte    = (const float*)d_in[1];
    const float* wpe    = (const float*)d_in[2];
    const float* ln1_w  = (const float*)d_in[3];
    const float* ln1_b  = (const float*)d_in[4];
    const float* attn_w = (const float*)d_in[5];
    const float* attn_b = (const float*)d_in[6];
    const float* proj_w = (const float*)d_in[7];
    const float* proj_b = (const float*)d_in[8];
    const float* ln2_w  = (const float*)d_in[9];
    const float* ln2_b  = (const float*)d_in[10];
    const float* fc_w   = (const float*)d_in[11];
    const float* fc_b   = (const float*)d_in[12];
    const float* fc2_w  = (const float*)d_in[13];
    const float* fc2_b  = (const float*)d_in[14];
    const float* lnf_w  = (const float*)d_in[15];
    const float* lnf_b  = (const float*)d_in[16];
    float* out = (float*)d_out;

    // ws layout: x f32[8192*512] | h bf16[8192*512] | big bf16[8192*2048] | weights bf16
    float* x   = (float*)d_ws;
    bf16* hbf  = (bf16*)(x + (size_t)NROWS * E_);
    bf16* big  = hbf + (size_t)NROWS * E_;
    bf16* wb   = big + (size_t)NROWS * 4 * E_;
    bf16* attn_wb = wb;
    bf16* proj_wb = attn_wb + (size_t)L_ * 3 * E_ * E_;
    bf16* fc_wb   = proj_wb + (size_t)L_ * E_ * E_;
    bf16* fc2_wb  = fc_wb   + (size_t)L_ * 4 * E_ * E_;
    bf16* wte_b   = fc2_wb  + (size_t)L_ * E_ * 4 * E_;

    // weight conversion (all sizes multiple of 1024)
    f2bf_kernel<<<(L_ * 3 * E_ * E_) / 1024, 256, 0, stream>>>(attn_w, attn_wb);
    f2bf_kernel<<<(L_ * E_ * E_) / 1024, 256, 0, stream>>>(proj_w, proj_wb);
    f2bf_kernel<<<(L_ * 4 * E_ * E_) / 1024, 256, 0, stream>>>(fc_w, fc_wb);
    f2bf_kernel<<<(L_ * E_ * 4 * E_) / 1024, 256, 0, stream>>>(fc2_w, fc2_wb);
    f2bf_kernel<<<(V_ * E_) / 1024, 256, 0, stream>>>(wte, wte_b);

    embed_kernel<<<NROWS * E_ / 256, 256, 0, stream>>>(idx, wte, wpe, x);

    for (int l = 0; l < L_; ++l) {
        layernorm_kernel<<<NROWS, 256, 0, stream>>>(x, ln1_w + l * E_, ln1_b + l * E_, hbf);
        gemm_mfma<0, 1, true><<<dim3(3 * E_ / 128, NROWS / 128), 256, 0, stream>>>(
            hbf, attn_wb + (size_t)l * 3 * E_ * E_, attn_b + l * 3 * E_, nullptr, big,
            NROWS, 3 * E_, E_);
        attn_flash<<<dim3(T_ / 64, H_, B_), 256, 0, stream>>>(big, hbf);
        gemm_mfma<0, 2, true><<<dim3(E_ / 128, NROWS / 128), 256, 0, stream>>>(
            hbf, proj_wb + (size_t)l * E_ * E_, proj_b + l * E_, x, nullptr,
            NROWS, E_, E_);
        layernorm_kernel<<<NROWS, 256, 0, stream>>>(x, ln2_w + l * E_, ln2_b + l * E_, hbf);
        gemm_mfma<1, 1, true><<<dim3(4 * E_ / 128, NROWS / 128), 256, 0, stream>>>(
            hbf, fc_wb + (size_t)l * 4 * E_ * E_, fc_b + l * 4 * E_, nullptr, big,
            NROWS, 4 * E_, E_);
        gemm_mfma<0, 2, true><<<dim3(E_ / 128, NROWS / 128), 256, 0, stream>>>(
            big, fc2_wb + (size_t)l * E_ * 4 * E_, fc2_b + l * E_, x, nullptr,
            NROWS, E_, 4 * E_);
    }
    layernorm_kernel<<<NROWS, 256, 0, stream>>>(x, lnf_w, lnf_b, hbf);
    gemm_mfma<0, 0, false><<<dim3(V_ / 128, NROWS / 128), 256, 0, stream>>>(
        hbf, wte_b, nullptr, out, nullptr, NROWS, V_, E_);
}

// Round 4
// 1256.598 us; speedup vs baseline: 11.3456x; 2.2475x over previous
//
#include <hip/hip_runtime.h>
#include <hip/hip_bf16.h>
#include <math.h>

#define B_ 4
#define T_ 2048
#define E_ 512
#define H_ 8
#define D_ 64
#define L_ 4
#define V_ 1024
#define NROWS (B_*T_)   // 8192
#define QBLK 128
#define KBLK 64
#define LPAD 72          // padded LDS row stride (bf16 elems): stride 144B -> conflict-free b128

typedef __hip_bfloat16 bf16;
typedef __attribute__((ext_vector_type(8))) short bf16x8;
typedef __attribute__((ext_vector_type(4))) float f32x4;

__device__ __forceinline__ float bf2f(short u) {
    union { float f; unsigned int i; } t;
    t.i = ((unsigned int)(unsigned short)u) << 16;
    return t.f;
}
__device__ __forceinline__ short f2bf_s(float f) {
    union { bf16 h; short s; } t; t.h = __float2bfloat16(f); return t.s;
}

__device__ __forceinline__ void gload_lds16(const bf16* g, bf16* l) {
    __builtin_amdgcn_global_load_lds((const __attribute__((address_space(1))) void*)g,
                                     (__attribute__((address_space(3))) void*)l, 16, 0, 0);
}

// ---------------- fp32 -> bf16 convert (n multiple of 1024) ----------------
__global__ void f2bf_kernel(const float* __restrict__ in, bf16* __restrict__ out) {
    int i = (blockIdx.x * blockDim.x + threadIdx.x) * 4;
    float4 v = *(const float4*)(in + i);
    union { bf16 h[4]; uint2 u; } t;
    t.h[0] = __float2bfloat16(v.x); t.h[1] = __float2bfloat16(v.y);
    t.h[2] = __float2bfloat16(v.z); t.h[3] = __float2bfloat16(v.w);
    *(uint2*)(out + i) = t.u;
}

// ---------------- embedding: x = wte[idx] + wpe[t] ----------------
__global__ void embed_kernel(const int* __restrict__ idx, const float* __restrict__ wte,
                             const float* __restrict__ wpe, float* __restrict__ x) {
    int i = blockIdx.x * blockDim.x + threadIdx.x;
    int row = i / E_;
    int e = i - row * E_;
    int t = row & (T_ - 1);
    int id = idx[row];
    x[i] = wte[id * E_ + e] + wpe[t * E_ + e];
}

// ---------------- layernorm: fp32 in, bf16 out ----------------
__global__ __launch_bounds__(256) void layernorm_kernel(const float* __restrict__ x,
                                 const float* __restrict__ w, const float* __restrict__ b,
                                 bf16* __restrict__ out) {
    __shared__ float red[256];
    int row = blockIdx.x;
    int tid = threadIdx.x;
    const float* xr = x + (size_t)row * E_;
    float v0 = xr[tid], v1 = xr[tid + 256];
    red[tid] = v0 + v1;
    __syncthreads();
    for (int st = 128; st > 0; st >>= 1) { if (tid < st) red[tid] += red[tid + st]; __syncthreads(); }
    float mean = red[0] * (1.0f / E_);
    __syncthreads();
    float d0 = v0 - mean, d1 = v1 - mean;
    red[tid] = d0 * d0 + d1 * d1;
    __syncthreads();
    for (int st = 128; st > 0; st >>= 1) { if (tid < st) red[tid] += red[tid + st]; __syncthreads(); }
    float rstd = rsqrtf(red[0] * (1.0f / E_) + 1e-5f);
    bf16* outr = out + (size_t)row * E_;
    outr[tid]       = __float2bfloat16(d0 * rstd * w[tid]       + b[tid]);
    outr[tid + 256] = __float2bfloat16(d1 * rstd * w[tid + 256] + b[tid + 256]);
}

// ---------------- bf16 MFMA GEMM (NT) ----------------
// OMODE: 0 = fp32 store, 1 = bf16 store, 2 = fp32 residual accumulate
template<int ACT, int OMODE, bool BIAS>
__global__ __launch_bounds__(256) void gemm_mfma(const bf16* __restrict__ A, const bf16* __restrict__ W,
        const float* __restrict__ bias, float* __restrict__ Cf, bf16* __restrict__ Cb,
        int M, int N, int K) {
    __shared__ __align__(16) bf16 As[128][32];
    __shared__ __align__(16) bf16 Bs[128][32];
    int tid = threadIdx.x;
    int lane = tid & 63, wid = tid >> 6;
    int wm = (wid >> 1) * 64, wn = (wid & 1) * 64;
    int m0 = blockIdx.y * 128, n0 = blockIdx.x * 128;

    int srow = wid * 32 + (lane >> 2);
    int scol = (lane & 3) * 8;
    const bf16* ga = A + (size_t)(m0 + srow) * K + scol;
    const bf16* gb = W + (size_t)(n0 + srow) * K + scol;
    int fr = lane & 15, fk = (lane >> 4) * 8;

    f32x4 acc[4][4];
    #pragma unroll
    for (int i = 0; i < 4; ++i)
        #pragma unroll
        for (int j = 0; j < 4; ++j) acc[i][j] = (f32x4){0.f, 0.f, 0.f, 0.f};

    for (int k0 = 0; k0 < K; k0 += 32) {
        gload_lds16(ga,          &As[wid * 32][0]);
        gload_lds16(ga + 16 * K, &As[wid * 32 + 16][0]);
        gload_lds16(gb,          &Bs[wid * 32][0]);
        gload_lds16(gb + 16 * K, &Bs[wid * 32 + 16][0]);
        ga += 32; gb += 32;
        __syncthreads();
        bf16x8 af[4], bff[4];
        #pragma unroll
        for (int i = 0; i < 4; ++i) af[i]  = *(const bf16x8*)&As[wm + i * 16 + fr][fk];
        #pragma unroll
        for (int j = 0; j < 4; ++j) bff[j] = *(const bf16x8*)&Bs[wn + j * 16 + fr][fk];
        #pragma unroll
        for (int i = 0; i < 4; ++i)
            #pragma unroll
            for (int j = 0; j < 4; ++j)
                acc[i][j] = __builtin_amdgcn_mfma_f32_16x16x32_bf16(af[i], bff[j], acc[i][j], 0, 0, 0);
        __syncthreads();
    }

    int orow = m0 + wm + (lane >> 4) * 4;
    int ocol = n0 + wn + (lane & 15);
    #pragma unroll
    for (int i = 0; i < 4; ++i) {
        #pragma unroll
        for (int j = 0; j < 4; ++j) {
            #pragma unroll
            for (int r = 0; r < 4; ++r) {
                int row = orow + i * 16 + r;
                int col = ocol + j * 16;
                float v = acc[i][j][r];
                if (BIAS) v += bias[col];
                if (ACT == 1) v = 0.5f * v * (1.0f + erff(v * 0.70710678118654752f));
                size_t off = (size_t)row * N + col;
                if (OMODE == 0) Cf[off] = v;
                else if (OMODE == 1) Cb[off] = __float2bfloat16(v);
                else Cf[off] += v;
            }
        }
    }
}

// ---------------- MFMA flash attention ----------------
// One block (4 waves) per (b, h, 128-row q-tile). Wave w owns q rows [w*32, w*32+32).
// KV tiles of 64. S = QK^T and O += P V via mfma_f32_16x16x32_bf16.
__global__ __launch_bounds__(256) void attn_mfma(const bf16* __restrict__ qkv, bf16* __restrict__ y) {
    __shared__ __align__(16) short Ks[KBLK][LPAD];    // [k][d]
    __shared__ __align__(16) short VsT[D_][LPAD];     // [d][k]  (V transposed)
    __shared__ __align__(16) short Ps[4][32][LPAD];   // per-wave P [q][k]
    const int qi = (gridDim.x - 1) - blockIdx.x;      // heaviest first
    const int h = blockIdx.y, b = blockIdx.z;
    const int q0 = qi * QBLK;
    const int tid = threadIdx.x;
    const int lane = tid & 63, wid = tid >> 6;
    const int wq = wid * 32;
    const int fr = lane & 15, fg = lane >> 4;
    const int fk = fg * 8;

    // hoist Q fragments into registers: A-frag = Q[row=fr][k=fk..fk+7]
    bf16x8 qf[2][2];
    #pragma unroll
    for (int m = 0; m < 2; ++m)
        #pragma unroll
        for (int kk = 0; kk < 2; ++kk) {
            int grow = q0 + wq + m * 16 + fr;
            qf[m][kk] = *(const bf16x8*)(qkv + (size_t)(b * T_ + grow) * (3 * E_) + h * D_ + kk * 32 + fk);
        }

    float mS[2][4], lS[2][4];
    f32x4 accO[2][4];
    #pragma unroll
    for (int m = 0; m < 2; ++m)
        #pragma unroll
        for (int r = 0; r < 4; ++r) { mS[m][r] = -INFINITY; lS[m][r] = 0.0f; }
    #pragma unroll
    for (int m = 0; m < 2; ++m)
        #pragma unroll
        for (int n = 0; n < 4; ++n) accO[m][n] = (f32x4){0.f, 0.f, 0.f, 0.f};

    const int wave_row_max = q0 + wq + 31;
    const int ntiles = 2 * qi + 2;

    for (int kt = 0; kt < ntiles; ++kt) {
        const int k0 = kt * KBLK;
        __syncthreads();   // previous tile's compute done; Ks/VsT free
        // stage K (row-major) and V (transposed), reg->LDS with padding
        #pragma unroll
        for (int it = 0; it < 4; ++it) {
            int f = it * 256 + tid;
            int kr = f >> 4, dc = (f & 15) * 4;
            short4 k4 = *(const short4*)(qkv + (size_t)(b * T_ + k0 + kr) * (3 * E_) + E_ + h * D_ + dc);
            *(short4*)&Ks[kr][dc] = k4;
            int vr = f & 63, dv = ((f >> 6) & 15) * 4;
            short4 v4 = *(const short4*)(qkv + (size_t)(b * T_ + k0 + vr) * (3 * E_) + 2 * E_ + h * D_ + dv);
            VsT[dv + 0][vr] = v4.x; VsT[dv + 1][vr] = v4.y;
            VsT[dv + 2][vr] = v4.z; VsT[dv + 3][vr] = v4.w;
        }
        __syncthreads();   // tiles staged

        if (k0 <= wave_row_max) {
            // ---- S = Q K^T ----
            bf16x8 kf[4][2];
            #pragma unroll
            for (int j = 0; j < 4; ++j)
                #pragma unroll
                for (int kk = 0; kk < 2; ++kk)
                    kf[j][kk] = *(const bf16x8*)&Ks[j * 16 + fr][kk * 32 + fk];
            f32x4 s[2][4];
            #pragma unroll
            for (int m = 0; m < 2; ++m)
                #pragma unroll
                for (int j = 0; j < 4; ++j) {
                    f32x4 a = (f32x4){0.f, 0.f, 0.f, 0.f};
                    #pragma unroll
                    for (int kk = 0; kk < 2; ++kk)
                        a = __builtin_amdgcn_mfma_f32_16x16x32_bf16(qf[m][kk], kf[j][kk], a, 0, 0, 0);
                    s[m][j] = a;
                }

            // ---- online softmax (C-layout: col = fr per j-frag, row = fg*4+r per m-frag) ----
            const bool domask = (k0 + KBLK - 1) > (q0 + wq);
            #pragma unroll
            for (int m = 0; m < 2; ++m) {
                #pragma unroll
                for (int r = 0; r < 4; ++r) {
                    int grow = q0 + wq + m * 16 + fg * 4 + r;
                    float rmax = -INFINITY;
                    #pragma unroll
                    for (int j = 0; j < 4; ++j) {
                        float sv = s[m][j][r] * 0.125f;
                        if (domask && (k0 + j * 16 + fr > grow)) sv = -INFINITY;
                        s[m][j][r] = sv;
                        rmax = fmaxf(rmax, sv);
                    }
                    rmax = fmaxf(rmax, __shfl_xor(rmax, 1));
                    rmax = fmaxf(rmax, __shfl_xor(rmax, 2));
                    rmax = fmaxf(rmax, __shfl_xor(rmax, 4));
                    rmax = fmaxf(rmax, __shfl_xor(rmax, 8));
                    float mnew = fmaxf(mS[m][r], rmax);
                    float corr = __expf(mS[m][r] - mnew);
                    float rl = 0.0f;
                    #pragma unroll
                    for (int j = 0; j < 4; ++j) {
                        float pv = __expf(s[m][j][r] - mnew);
                        s[m][j][r] = pv;
                        rl += pv;
                    }
                    rl += __shfl_xor(rl, 1);
                    rl += __shfl_xor(rl, 2);
                    rl += __shfl_xor(rl, 4);
                    rl += __shfl_xor(rl, 8);
                    lS[m][r] = lS[m][r] * corr + rl;
                    mS[m][r] = mnew;
                    #pragma unroll
                    for (int n = 0; n < 4; ++n) accO[m][n][r] *= corr;
                }
            }

            // ---- P (C-layout) -> per-wave LDS -> A-frags ----
            #pragma unroll
            for (int m = 0; m < 2; ++m)
                #pragma unroll
                for (int j = 0; j < 4; ++j)
                    #pragma unroll
                    for (int r = 0; r < 4; ++r)
                        Ps[wid][m * 16 + fg * 4 + r][j * 16 + fr] = f2bf_s(s[m][j][r]);

            // ---- O += P V ----
            bf16x8 pa[2][2], vb[4][2];
            #pragma unroll
            for (int m = 0; m < 2; ++m)
                #pragma unroll
                for (int kk = 0; kk < 2; ++kk)
                    pa[m][kk] = *(const bf16x8*)&Ps[wid][m * 16 + fr][kk * 32 + fk];
            #pragma unroll
            for (int n = 0; n < 4; ++n)
                #pragma unroll
                for (int kk = 0; kk < 2; ++kk)
                    vb[n][kk] = *(const bf16x8*)&VsT[n * 16 + fr][kk * 32 + fk];
            #pragma unroll
            for (int m = 0; m < 2; ++m)
                #pragma unroll
                for (int n = 0; n < 4; ++n)
                    #pragma unroll
                    for (int kk = 0; kk < 2; ++kk)
                        accO[m][n] = __builtin_amdgcn_mfma_f32_16x16x32_bf16(pa[m][kk], vb[n][kk], accO[m][n], 0, 0, 0);
        }
    }

    // ---- epilogue: O / l ----
    #pragma unroll
    for (int m = 0; m < 2; ++m)
        #pragma unroll
        for (int r = 0; r < 4; ++r) {
            int grow = q0 + wq + m * 16 + fg * 4 + r;
            float inv = 1.0f / lS[m][r];
            #pragma unroll
            for (int n = 0; n < 4; ++n)
                y[(size_t)(b * T_ + grow) * E_ + h * D_ + n * 16 + fr] =
                    __float2bfloat16(accO[m][n][r] * inv);
        }
}

extern "C" void kernel_launch(void* const* d_in, const int* in_sizes, int n_in,
                              void* d_out, int out_size, void* d_ws, size_t ws_size,
                              hipStream_t stream) {
    const int*   idx    = (const int*)d_in[0];
    const float* wte    = (const float*)d_in[1];
    const float* wpe    = (const float*)d_in[2];
    const float* ln1_w  = (const float*)d_in[3];
    const float* ln1_b  = (const float*)d_in[4];
    const float* attn_w = (const float*)d_in[5];
    const float* attn_b = (const float*)d_in[6];
    const float* proj_w = (const float*)d_in[7];
    const float* proj_b = (const float*)d_in[8];
    const float* ln2_w  = (const float*)d_in[9];
    const float* ln2_b  = (const float*)d_in[10];
    const float* fc_w   = (const float*)d_in[11];
    const float* fc_b   = (const float*)d_in[12];
    const float* fc2_w  = (const float*)d_in[13];
    const float* fc2_b  = (const float*)d_in[14];
    const float* lnf_w  = (const float*)d_in[15];
    const float* lnf_b  = (const float*)d_in[16];
    float* out = (float*)d_out;

    // ws layout: x f32[8192*512] | h bf16[8192*512] | big bf16[8192*2048] | weights bf16
    float* x   = (float*)d_ws;
    bf16* hbf  = (bf16*)(x + (size_t)NROWS * E_);
    bf16* big  = hbf + (size_t)NROWS * E_;
    bf16* wb   = big + (size_t)NROWS * 4 * E_;
    bf16* attn_wb = wb;
    bf16* proj_wb = attn_wb + (size_t)L_ * 3 * E_ * E_;
    bf16* fc_wb   = proj_wb + (size_t)L_ * E_ * E_;
    bf16* fc2_wb  = fc_wb   + (size_t)L_ * 4 * E_ * E_;
    bf16* wte_b   = fc2_wb  + (size_t)L_ * E_ * 4 * E_;

    f2bf_kernel<<<(L_ * 3 * E_ * E_) / 1024, 256, 0, stream>>>(attn_w, attn_wb);
    f2bf_kernel<<<(L_ * E_ * E_) / 1024, 256, 0, stream>>>(proj_w, proj_wb);
    f2bf_kernel<<<(L_ * 4 * E_ * E_) / 1024, 256, 0, stream>>>(fc_w, fc_wb);
    f2bf_kernel<<<(L_ * E_ * 4 * E_) / 1024, 256, 0, stream>>>(fc2_w, fc2_wb);
    f2bf_kernel<<<(V_ * E_) / 1024, 256, 0, stream>>>(wte, wte_b);

    embed_kernel<<<NROWS * E_ / 256, 256, 0, stream>>>(idx, wte, wpe, x);

    for (int l = 0; l < L_; ++l) {
        layernorm_kernel<<<NROWS, 256, 0, stream>>>(x, ln1_w + l * E_, ln1_b + l * E_, hbf);
        gemm_mfma<0, 1, true><<<dim3(3 * E_ / 128, NROWS / 128), 256, 0, stream>>>(
            hbf, attn_wb + (size_t)l * 3 * E_ * E_, attn_b + l * 3 * E_, nullptr, big,
            NROWS, 3 * E_, E_);
        attn_mfma<<<dim3(T_ / QBLK, H_, B_), 256, 0, stream>>>(big, hbf);
        gemm_mfma<0, 2, true><<<dim3(E_ / 128, NROWS / 128), 256, 0, stream>>>(
            hbf, proj_wb + (size_t)l * E_ * E_, proj_b + l * E_, x, nullptr,
            NROWS, E_, E_);
        layernorm_kernel<<<NROWS, 256, 0, stream>>>(x, ln2_w + l * E_, ln2_b + l * E_, hbf);
        gemm_mfma<1, 1, true><<<dim3(4 * E_ / 128, NROWS / 128), 256, 0, stream>>>(
            hbf, fc_wb + (size_t)l * 4 * E_ * E_, fc_b + l * 4 * E_, nullptr, big,
            NROWS, 4 * E_, E_);
        gemm_mfma<0, 2, true><<<dim3(E_ / 128, NROWS / 128), 256, 0, stream>>>(
            big, fc2_wb + (size_t)l * E_ * 4 * E_, fc2_b + l * E_, x, nullptr,
            NROWS, E_, 4 * E_);
    }
    layernorm_kernel<<<NROWS, 256, 0, stream>>>(x, lnf_w, lnf_b, hbf);
    gemm_mfma<0, 0, false><<<dim3(V_ / 128, NROWS / 128), 256, 0, stream>>>(
        hbf, wte_b, nullptr, out, nullptr, NROWS, V_, E_);
}

// Round 5
// 1141.199 us; speedup vs baseline: 12.4929x; 1.1011x over previous
//
#include <hip/hip_runtime.h>
#include <hip/hip_bf16.h>
#include <math.h>

#define B_ 4
#define T_ 2048
#define E_ 512
#define H_ 8
#define D_ 64
#define L_ 4
#define V_ 1024
#define NROWS (B_*T_)   // 8192
#define QBLK 128        // q rows per block (8 waves x 16)
#define KBLK 64
#define LPAD 72         // LDS row stride (bf16): 144B -> b128 reads conflict-free

typedef __hip_bfloat16 bf16;
typedef __attribute__((ext_vector_type(8))) short bf16x8;
typedef __attribute__((ext_vector_type(4))) float f32x4;

__device__ __forceinline__ short f2bf_s(float f) {
    union { bf16 h; short s; } t; t.h = __float2bfloat16(f); return t.s;
}

__device__ __forceinline__ void gload_lds16(const bf16* g, bf16* l) {
    __builtin_amdgcn_global_load_lds((const __attribute__((address_space(1))) void*)g,
                                     (__attribute__((address_space(3))) void*)l, 16, 0, 0);
}

// ---------------- fp32 -> bf16 convert (n multiple of 1024) ----------------
__global__ void f2bf_kernel(const float* __restrict__ in, bf16* __restrict__ out) {
    int i = (blockIdx.x * blockDim.x + threadIdx.x) * 4;
    float4 v = *(const float4*)(in + i);
    union { bf16 h[4]; uint2 u; } t;
    t.h[0] = __float2bfloat16(v.x); t.h[1] = __float2bfloat16(v.y);
    t.h[2] = __float2bfloat16(v.z); t.h[3] = __float2bfloat16(v.w);
    *(uint2*)(out + i) = t.u;
}

// ---------------- embedding ----------------
__global__ void embed_kernel(const int* __restrict__ idx, const float* __restrict__ wte,
                             const float* __restrict__ wpe, float* __restrict__ x) {
    int i = blockIdx.x * blockDim.x + threadIdx.x;
    int row = i / E_;
    int e = i - row * E_;
    int t = row & (T_ - 1);
    int id = idx[row];
    x[i] = wte[id * E_ + e] + wpe[t * E_ + e];
}

// ---------------- layernorm: fp32 in, bf16 out ----------------
__global__ __launch_bounds__(256) void layernorm_kernel(const float* __restrict__ x,
                                 const float* __restrict__ w, const float* __restrict__ b,
                                 bf16* __restrict__ out) {
    __shared__ float red[256];
    int row = blockIdx.x;
    int tid = threadIdx.x;
    const float* xr = x + (size_t)row * E_;
    float v0 = xr[tid], v1 = xr[tid + 256];
    red[tid] = v0 + v1;
    __syncthreads();
    for (int st = 128; st > 0; st >>= 1) { if (tid < st) red[tid] += red[tid + st]; __syncthreads(); }
    float mean = red[0] * (1.0f / E_);
    __syncthreads();
    float d0 = v0 - mean, d1 = v1 - mean;
    red[tid] = d0 * d0 + d1 * d1;
    __syncthreads();
    for (int st = 128; st > 0; st >>= 1) { if (tid < st) red[tid] += red[tid + st]; __syncthreads(); }
    float rstd = rsqrtf(red[0] * (1.0f / E_) + 1e-5f);
    bf16* outr = out + (size_t)row * E_;
    outr[tid]       = __float2bfloat16(d0 * rstd * w[tid]       + b[tid]);
    outr[tid + 256] = __float2bfloat16(d1 * rstd * w[tid + 256] + b[tid + 256]);
}

// ---------------- bf16 MFMA GEMM (NT) ----------------
// OMODE: 0 = fp32 store, 1 = bf16 store, 2 = fp32 residual accumulate
template<int ACT, int OMODE, bool BIAS>
__global__ __launch_bounds__(256) void gemm_mfma(const bf16* __restrict__ A, const bf16* __restrict__ W,
        const float* __restrict__ bias, float* __restrict__ Cf, bf16* __restrict__ Cb,
        int M, int N, int K) {
    __shared__ __align__(16) bf16 As[128][32];
    __shared__ __align__(16) bf16 Bs[128][32];
    int tid = threadIdx.x;
    int lane = tid & 63, wid = tid >> 6;
    int wm = (wid >> 1) * 64, wn = (wid & 1) * 64;
    int m0 = blockIdx.y * 128, n0 = blockIdx.x * 128;

    int srow = wid * 32 + (lane >> 2);
    int scol = (lane & 3) * 8;
    const bf16* ga = A + (size_t)(m0 + srow) * K + scol;
    const bf16* gb = W + (size_t)(n0 + srow) * K + scol;
    int fr = lane & 15, fk = (lane >> 4) * 8;

    f32x4 acc[4][4];
    #pragma unroll
    for (int i = 0; i < 4; ++i)
        #pragma unroll
        for (int j = 0; j < 4; ++j) acc[i][j] = (f32x4){0.f, 0.f, 0.f, 0.f};

    for (int k0 = 0; k0 < K; k0 += 32) {
        gload_lds16(ga,          &As[wid * 32][0]);
        gload_lds16(ga + 16 * K, &As[wid * 32 + 16][0]);
        gload_lds16(gb,          &Bs[wid * 32][0]);
        gload_lds16(gb + 16 * K, &Bs[wid * 32 + 16][0]);
        ga += 32; gb += 32;
        __syncthreads();
        bf16x8 af[4], bff[4];
        #pragma unroll
        for (int i = 0; i < 4; ++i) af[i]  = *(const bf16x8*)&As[wm + i * 16 + fr][fk];
        #pragma unroll
        for (int j = 0; j < 4; ++j) bff[j] = *(const bf16x8*)&Bs[wn + j * 16 + fr][fk];
        #pragma unroll
        for (int i = 0; i < 4; ++i)
            #pragma unroll
            for (int j = 0; j < 4; ++j)
                acc[i][j] = __builtin_amdgcn_mfma_f32_16x16x32_bf16(af[i], bff[j], acc[i][j], 0, 0, 0);
        __syncthreads();
    }

    int orow = m0 + wm + (lane >> 4) * 4;
    int ocol = n0 + wn + (lane & 15);
    #pragma unroll
    for (int i = 0; i < 4; ++i) {
        #pragma unroll
        for (int j = 0; j < 4; ++j) {
            #pragma unroll
            for (int r = 0; r < 4; ++r) {
                int row = orow + i * 16 + r;
                int col = ocol + j * 16;
                float v = acc[i][j][r];
                if (BIAS) v += bias[col];
                if (ACT == 1) v = 0.5f * v * (1.0f + erff(v * 0.70710678118654752f));
                size_t off = (size_t)row * N + col;
                if (OMODE == 0) Cf[off] = v;
                else if (OMODE == 1) Cb[off] = __float2bfloat16(v);
                else Cf[off] += v;
            }
        }
    }
}

// ---------------- MFMA flash attention, swapped-QK^T dataflow ----------------
// 8 waves per block (512 thr); wave w owns q rows [q0+w*16, q0+w*16+16).
// S^T = mfma(K, Q): per-lane q = lane&15, k = (lane>>4)*4+r (+16j) -> lane-local softmax.
// Double-buffered K/V tiles, ONE barrier per tile.
__global__ __launch_bounds__(512, 4) void attn_mfma(const bf16* __restrict__ qkv, bf16* __restrict__ y) {
    __shared__ __align__(16) short Ks[2][KBLK][LPAD];    // [buf][k][d]
    __shared__ __align__(16) short VsT[2][D_][LPAD];     // [buf][d][k]
    __shared__ __align__(16) short Ps[8][16][LPAD];      // per-wave P [q][k]
    const int qi = (gridDim.x - 1) - blockIdx.x;          // heaviest first
    const int h = blockIdx.y, b = blockIdx.z;
    const int q0 = qi * QBLK;
    const int tid = threadIdx.x;
    const int lane = tid & 63, wid = tid >> 6;
    const int fr = lane & 15, fg = lane >> 4;
    const int qmin = q0 + wid * 16;
    const int qrow = qmin + fr;                           // this lane's q

    // staging assignment: thread covers (row skr, d-cols sdc..sdc+7) of K and V
    const int skr = tid >> 3;           // 0..63
    const int sdc = (tid & 7) * 8;      // 0..56
    const size_t srowbase = (size_t)(b * T_ + skr) * (3 * E_) + h * D_ + sdc;

    // Q B-fragments (col=q=fr, inner d)
    bf16x8 qf[2];
    #pragma unroll
    for (int kk = 0; kk < 2; ++kk)
        qf[kk] = *(const bf16x8*)(qkv + (size_t)(b * T_ + qrow) * (3 * E_) + h * D_ + kk * 32 + fg * 8);

    float m_run = -INFINITY, l_run = 0.0f;
    f32x4 accO[4];
    #pragma unroll
    for (int n = 0; n < 4; ++n) accO[n] = (f32x4){0.f, 0.f, 0.f, 0.f};

    const int ntiles = (q0 + QBLK) / KBLK;   // 2*qi+2
    const int rot = tid & 7;

    // prologue: stage tile 0 into buf 0
    {
        uint4 kreg = *(const uint4*)(qkv + srowbase + E_);
        uint4 vreg = *(const uint4*)(qkv + srowbase + 2 * E_);
        *(uint4*)&Ks[0][skr][sdc] = kreg;
        union { uint4 u; short s[8]; } vv; vv.u = vreg;
        #pragma unroll
        for (int jj = 0; jj < 8; ++jj) {
            int j = (jj + rot) & 7;                      // rotation kills 8-way write conflict
            VsT[0][sdc + j][skr] = vv.s[j];
        }
    }
    __syncthreads();

    for (int kt = 0; kt < ntiles; ++kt) {
        const int cur = kt & 1;
        const int k0 = kt * KBLK;
        const bool have_next = (kt + 1 < ntiles);
        uint4 kreg, vreg;
        if (have_next) {                                  // issue next-tile loads (overlap compute)
            size_t nb = srowbase + (size_t)(kt + 1) * KBLK * (3 * E_);
            kreg = *(const uint4*)(qkv + nb + E_);
            vreg = *(const uint4*)(qkv + nb + 2 * E_);
        }

        if (k0 <= qmin + 15) {                            // wave active for this tile
            // ---- S^T = K Q^T : st[j] col=q=fr, row=k=fg*4+r (+16j) ----
            f32x4 st[4];
            #pragma unroll
            for (int j = 0; j < 4; ++j) {
                f32x4 a = (f32x4){0.f, 0.f, 0.f, 0.f};
                #pragma unroll
                for (int kk = 0; kk < 2; ++kk) {
                    bf16x8 kf = *(const bf16x8*)&Ks[cur][j * 16 + fr][kk * 32 + fg * 8];
                    a = __builtin_amdgcn_mfma_f32_16x16x32_bf16(kf, qf[kk], a, 0, 0, 0);
                }
                st[j] = a;
            }

            // ---- lane-local softmax over k ----
            const bool domask = (k0 + KBLK - 1) > qmin;
            float mx = -INFINITY;
            #pragma unroll
            for (int j = 0; j < 4; ++j)
                #pragma unroll
                for (int r = 0; r < 4; ++r) {
                    float sv = st[j][r] * 0.125f;
                    if (domask && (k0 + j * 16 + fg * 4 + r > qrow)) sv = -INFINITY;
                    st[j][r] = sv;
                    mx = fmaxf(mx, sv);
                }
            mx = fmaxf(mx, __shfl_xor(mx, 16));
            mx = fmaxf(mx, __shfl_xor(mx, 32));
            float mnew = fmaxf(m_run, mx);
            float corr = __expf(m_run - mnew);
            float rl = 0.0f;
            #pragma unroll
            for (int j = 0; j < 4; ++j) {
                short4 pk;
                float p0 = __expf(st[j][0] - mnew), p1 = __expf(st[j][1] - mnew);
                float p2 = __expf(st[j][2] - mnew), p3 = __expf(st[j][3] - mnew);
                rl += (p0 + p1) + (p2 + p3);
                pk.x = f2bf_s(p0); pk.y = f2bf_s(p1); pk.z = f2bf_s(p2); pk.w = f2bf_s(p3);
                *(short4*)&Ps[wid][fr][j * 16 + fg * 4] = pk;   // vectorized P write
            }
            rl += __shfl_xor(rl, 16);
            rl += __shfl_xor(rl, 32);
            l_run = l_run * corr + rl;
            m_run = mnew;

            // ---- redistribute corr to accO rows (q = fg*4+r), rescale ----
            #pragma unroll
            for (int r = 0; r < 4; ++r) {
                float cr = __shfl(corr, fg * 4 + r);
                #pragma unroll
                for (int n = 0; n < 4; ++n) accO[n][r] *= cr;
            }

            // ---- O += P V ----
            bf16x8 pa[2];
            #pragma unroll
            for (int kk = 0; kk < 2; ++kk)
                pa[kk] = *(const bf16x8*)&Ps[wid][fr][kk * 32 + fg * 8];
            #pragma unroll
            for (int n = 0; n < 4; ++n)
                #pragma unroll
                for (int kk = 0; kk < 2; ++kk) {
                    bf16x8 vb = *(const bf16x8*)&VsT[cur][n * 16 + fr][kk * 32 + fg * 8];
                    accO[n] = __builtin_amdgcn_mfma_f32_16x16x32_bf16(pa[kk], vb, accO[n], 0, 0, 0);
                }
        }

        // ---- write next tile into the other buffer ----
        if (have_next) {
            const int nxt = cur ^ 1;
            *(uint4*)&Ks[nxt][skr][sdc] = kreg;
            union { uint4 u; short s[8]; } vv; vv.u = vreg;
            #pragma unroll
            for (int jj = 0; jj < 8; ++jj) {
                int j = (jj + rot) & 7;
                VsT[nxt][sdc + j][skr] = vv.s[j];
            }
        }
        __syncthreads();
    }

    // ---- epilogue: O / l ----
    float linv = 1.0f / l_run;
    #pragma unroll
    for (int r = 0; r < 4; ++r) {
        float lr = __shfl(linv, fg * 4 + r);
        int gq = qmin + fg * 4 + r;
        #pragma unroll
        for (int n = 0; n < 4; ++n)
            y[(size_t)(b * T_ + gq) * E_ + h * D_ + n * 16 + fr] =
                __float2bfloat16(accO[n][r] * lr);
    }
}

extern "C" void kernel_launch(void* const* d_in, const int* in_sizes, int n_in,
                              void* d_out, int out_size, void* d_ws, size_t ws_size,
                              hipStream_t stream) {
    const int*   idx    = (const int*)d_in[0];
    const float* wte    = (const float*)d_in[1];
    const float* wpe    = (const float*)d_in[2];
    const float* ln1_w  = (const float*)d_in[3];
    const float* ln1_b  = (const float*)d_in[4];
    const float* attn_w = (const float*)d_in[5];
    const float* attn_b = (const float*)d_in[6];
    const float* proj_w = (const float*)d_in[7];
    const float* proj_b = (const float*)d_in[8];
    const float* ln2_w  = (const float*)d_in[9];
    const float* ln2_b  = (const float*)d_in[10];
    const float* fc_w   = (const float*)d_in[11];
    const float* fc_b   = (const float*)d_in[12];
    const float* fc2_w  = (const float*)d_in[13];
    const float* fc2_b  = (const float*)d_in[14];
    const float* lnf_w  = (const float*)d_in[15];
    const float* lnf_b  = (const float*)d_in[16];
    float* out = (float*)d_out;

    // ws layout: x f32[8192*512] | h bf16[8192*512] | big bf16[8192*2048] | weights bf16
    float* x   = (float*)d_ws;
    bf16* hbf  = (bf16*)(x + (size_t)NROWS * E_);
    bf16* big  = hbf + (size_t)NROWS * E_;
    bf16* wb   = big + (size_t)NROWS * 4 * E_;
    bf16* attn_wb = wb;
    bf16* proj_wb = attn_wb + (size_t)L_ * 3 * E_ * E_;
    bf16* fc_wb   = proj_wb + (size_t)L_ * E_ * E_;
    bf16* fc2_wb  = fc_wb   + (size_t)L_ * 4 * E_ * E_;
    bf16* wte_b   = fc2_wb  + (size_t)L_ * E_ * 4 * E_;

    f2bf_kernel<<<(L_ * 3 * E_ * E_) / 1024, 256, 0, stream>>>(attn_w, attn_wb);
    f2bf_kernel<<<(L_ * E_ * E_) / 1024, 256, 0, stream>>>(proj_w, proj_wb);
    f2bf_kernel<<<(L_ * 4 * E_ * E_) / 1024, 256, 0, stream>>>(fc_w, fc_wb);
    f2bf_kernel<<<(L_ * E_ * 4 * E_) / 1024, 256, 0, stream>>>(fc2_w, fc2_wb);
    f2bf_kernel<<<(V_ * E_) / 1024, 256, 0, stream>>>(wte, wte_b);

    embed_kernel<<<NROWS * E_ / 256, 256, 0, stream>>>(idx, wte, wpe, x);

    for (int l = 0; l < L_; ++l) {
        layernorm_kernel<<<NROWS, 256, 0, stream>>>(x, ln1_w + l * E_, ln1_b + l * E_, hbf);
        gemm_mfma<0, 1, true><<<dim3(3 * E_ / 128, NROWS / 128), 256, 0, stream>>>(
            hbf, attn_wb + (size_t)l * 3 * E_ * E_, attn_b + l * 3 * E_, nullptr, big,
            NROWS, 3 * E_, E_);
        attn_mfma<<<dim3(T_ / QBLK, H_, B_), 512, 0, stream>>>(big, hbf);
        gemm_mfma<0, 2, true><<<dim3(E_ / 128, NROWS / 128), 256, 0, stream>>>(
            hbf, proj_wb + (size_t)l * E_ * E_, proj_b + l * E_, x, nullptr,
            NROWS, E_, E_);
        layernorm_kernel<<<NROWS, 256, 0, stream>>>(x, ln2_w + l * E_, ln2_b + l * E_, hbf);
        gemm_mfma<1, 1, true><<<dim3(4 * E_ / 128, NROWS / 128), 256, 0, stream>>>(
            hbf, fc_wb + (size_t)l * 4 * E_ * E_, fc_b + l * 4 * E_, nullptr, big,
            NROWS, 4 * E_, E_);
        gemm_mfma<0, 2, true><<<dim3(E_ / 128, NROWS / 128), 256, 0, stream>>>(
            big, fc2_wb + (size_t)l * E_ * 4 * E_, fc2_b + l * E_, x, nullptr,
            NROWS, E_, 4 * E_);
    }
    layernorm_kernel<<<NROWS, 256, 0, stream>>>(x, lnf_w, lnf_b, hbf);
    gemm_mfma<0, 0, false><<<dim3(V_ / 128, NROWS / 128), 256, 0, stream>>>(
        hbf, wte_b, nullptr, out, nullptr, NROWS, V_, E_);
}